// Round 8
// baseline (116.200 us; speedup 1.0000x reference)
//
#include <hip/hip_runtime.h>
#include <math.h>

#define NTOK 16384
#define DDIM 4096
#define NEXP 64
#define TAU  2e-4f
#define WS_LO 262144   // short-offset of the lo-plane inside d_ws

typedef short bf16x8 __attribute__((ext_vector_type(8)));
typedef float f32x4  __attribute__((ext_vector_type(4)));

__device__ __forceinline__ unsigned short bf16_rne(float f) {
  unsigned u = __float_as_uint(f);
  u += 0x7fffu + ((u >> 16) & 1u);
  return (unsigned short)(u >> 16);
}

__device__ __forceinline__ void split4(float4 v, uint2& hi, uint2& lo) {
  unsigned h0 = bf16_rne(v.x), h1 = bf16_rne(v.y), h2 = bf16_rne(v.z), h3 = bf16_rne(v.w);
  float r0 = v.x - __uint_as_float(h0 << 16);
  float r1 = v.y - __uint_as_float(h1 << 16);
  float r2 = v.z - __uint_as_float(h2 << 16);
  float r3 = v.w - __uint_as_float(h3 << 16);
  unsigned l0 = bf16_rne(r0), l1 = bf16_rne(r1), l2 = bf16_rne(r2), l3 = bf16_rne(r3);
  hi = make_uint2(h0 | (h1 << 16), h2 | (h3 << 16));
  lo = make_uint2(l0 | (l1 << 16), l2 | (l3 << 16));
}

__device__ __forceinline__ void split4v(f32x4 v, uint2& hi, uint2& lo) {
  unsigned h0 = bf16_rne(v[0]), h1 = bf16_rne(v[1]), h2 = bf16_rne(v[2]), h3 = bf16_rne(v[3]);
  float r0 = v[0] - __uint_as_float(h0 << 16);
  float r1 = v[1] - __uint_as_float(h1 << 16);
  float r2 = v[2] - __uint_as_float(h2 << 16);
  float r3 = v[3] - __uint_as_float(h3 << 16);
  unsigned l0 = bf16_rne(r0), l1 = bf16_rne(r1), l2 = bf16_rne(r2), l3 = bf16_rne(r3);
  hi = make_uint2(h0 | (h1 << 16), h2 | (h3 << 16));
  lo = make_uint2(l0 | (l1 << 16), l2 | (l3 << 16));
}

__device__ __forceinline__ bf16x8 mk8(uint2 a, uint2 b) {
  union { uint4 u; bf16x8 v; } t;
  t.u = make_uint4(a.x, a.y, b.x, b.y);
  return t.v;
}

__device__ __forceinline__ void gld_lds16(const float* g, char* l) {
  __builtin_amdgcn_global_load_lds((const __attribute__((address_space(1))) void*)g,
                                   (__attribute__((address_space(3))) void*)l,
                                   16, 0, 0);
}

__device__ __forceinline__ bool better(float va, int ia, float vb, int ib) {
  return (va > vb) || (va == vb && ia < ib);
}
__device__ __forceinline__ bool betterd(double va, int ia, double vb, int ib) {
  return (va > vb) || (va == vb && ia < ib);
}
#define CE(va, ia, vb, ib) { if (better(vb, ib, va, ia)) { float _tv = va; va = vb; vb = _tv; int _ti = ia; ia = ib; ib = _ti; } }

// ---- kernel 1: split W (fp32) into bf16 hi/lo, MFMA-fragment-linear, once ----
__global__ __launch_bounds__(256)
void presplit_w(const float* __restrict__ w, short* __restrict__ ws) {
  const int tid = blockIdx.x * 256 + threadIdx.x;  // 32768 threads
  const int e = tid >> 9;          // expert 0..63
  const int o = tid & 511;         // k-octet 0..511
  const int c = o >> 2, q = o & 3;
  const int l = (e & 15) + 16 * q;
  const int g = e >> 4;
  const float* src = w + (size_t)e * DDIM + o * 8;
  float4 v0 = *(const float4*)src;
  float4 v1 = *(const float4*)(src + 4);
  uint2 h0, s0, h1, s1;
  split4(v0, h0, s0);
  split4(v1, h1, s1);
  const int off = c * 2048 + g * 512 + l * 8;
  *(uint4*)(ws + off)         = make_uint4(h0.x, h0.y, h1.x, h1.y);
  *(uint4*)(ws + WS_LO + off) = make_uint4(s0.x, s0.y, s1.x, s1.y);
}

// ---- fp64 recompute for near-tie tokens (rare); executed by one full wave ----
__device__ __noinline__ void fixup_token(const float* __restrict__ x,
                                         const float* __restrict__ wgt,
                                         float* __restrict__ out_idx,
                                         float* __restrict__ out_wt,
                                         int tok, unsigned pk, int l) {
  const int e0 = pk & 255, e1 = (pk >> 8) & 255, e2 = (pk >> 16) & 255, e3 = (pk >> 24) & 255;
  const float* xr = x   + (size_t)tok * DDIM + l * 64;
  const float* w0 = wgt + (size_t)e0 * DDIM + l * 64;
  const float* w1 = wgt + (size_t)e1 * DDIM + l * 64;
  const float* w2 = wgt + (size_t)e2 * DDIM + l * 64;
  const float* w3 = wgt + (size_t)e3 * DDIM + l * 64;
  double s0 = 0.0, s1 = 0.0, s2 = 0.0, s3 = 0.0;
#pragma unroll 4
  for (int j = 0; j < 64; j += 4) {
    float4 xv = *(const float4*)(xr + j);
    float4 av = *(const float4*)(w0 + j);
    s0 = fma((double)xv.x, (double)av.x, s0); s0 = fma((double)xv.y, (double)av.y, s0);
    s0 = fma((double)xv.z, (double)av.z, s0); s0 = fma((double)xv.w, (double)av.w, s0);
    av = *(const float4*)(w1 + j);
    s1 = fma((double)xv.x, (double)av.x, s1); s1 = fma((double)xv.y, (double)av.y, s1);
    s1 = fma((double)xv.z, (double)av.z, s1); s1 = fma((double)xv.w, (double)av.w, s1);
    av = *(const float4*)(w2 + j);
    s2 = fma((double)xv.x, (double)av.x, s2); s2 = fma((double)xv.y, (double)av.y, s2);
    s2 = fma((double)xv.z, (double)av.z, s2); s2 = fma((double)xv.w, (double)av.w, s2);
    av = *(const float4*)(w3 + j);
    s3 = fma((double)xv.x, (double)av.x, s3); s3 = fma((double)xv.y, (double)av.y, s3);
    s3 = fma((double)xv.z, (double)av.z, s3); s3 = fma((double)xv.w, (double)av.w, s3);
  }
#pragma unroll
  for (int m = 1; m < 64; m <<= 1) {
    s0 += __shfl_xor(s0, m);
    s1 += __shfl_xor(s1, m);
    s2 += __shfl_xor(s2, m);
    s3 += __shfl_xor(s3, m);
  }
  if (l == 0) {
    double v0 = s0, v1 = s1, v2 = s2, v3 = s3;
    int i0 = e0, i1 = e1, i2 = e2, i3 = e3;
    if (betterd(v1, i1, v0, i0)) { double tv = v0; v0 = v1; v1 = tv; int ti = i0; i0 = i1; i1 = ti; }
    if (betterd(v3, i3, v2, i2)) { double tv = v2; v2 = v3; v3 = tv; int ti = i2; i2 = i3; i3 = ti; }
    if (betterd(v2, i2, v0, i0)) { double tv = v0; v0 = v2; v2 = tv; int ti = i0; i0 = i2; i2 = ti; }
    if (betterd(v3, i3, v1, i1)) { double tv = v1; v1 = v3; v3 = tv; int ti = i1; i1 = i3; i3 = ti; }
    if (betterd(v2, i2, v1, i1)) { double tv = v1; v1 = v2; v2 = tv; int ti = i1; i1 = i2; i2 = ti; }
    double ex = exp(v1 - v0);
    double den = 1.0 + ex;
    out_idx[tok * 2 + 0] = (float)i0;
    out_idx[tok * 2 + 1] = (float)i1;
    out_wt[tok * 2 + 0]  = (float)(1.0 / den);
    out_wt[tok * 2 + 1]  = (float)(ex / den);
  }
}

// ---- kernel 2: barrier-free, 1KiB-contiguous-per-instruction X streaming ----
// 1024 blocks x 128 thr (2 waves = 2 K-halves). Block = 16 tokens x 64 experts.
// Per wave: 16 rows x 2048k; macro = 16 rows x 256k = 16 KiB staged as 16
// gld_lds, each ONE row's 1 KiB (sequential per-row streams, m13-granularity).
// LDS: 2 waves x 2 slots x 16 KiB = 64 KiB; 2 blocks/CU.
__global__ __launch_bounds__(128, 1)
void router_main(const float* __restrict__ x, const float* __restrict__ wgt,
                 const short* __restrict__ ws, float* __restrict__ out) {
  __shared__ __align__(16) char ldsbuf[65536];

  const int u = threadIdx.x;
  const int l = u & 63;
  const int kh = u >> 6;           // K-half 0/1
  const int tokBase = blockIdx.x * 16;
  const int row = l & 15;
  const int hq = l >> 4;

  const unsigned ldsbase =
      (unsigned)(size_t)(__attribute__((address_space(3))) char*)&ldsbuf[0];
  const unsigned abase = ldsbase + kh * 32768 + row * 1024;
  const unsigned lofs = (unsigned)((((hq * 2) ^ (row & 7)) << 4));

  // per-lane swizzled source offsets within a 1 KiB row segment (rule #21:
  // linear LDS dest + inverse-swizzled global source; footprint unchanged)
  const int lz = l * 16;
  const int sz0 = lz ^ 0x00, sz1 = lz ^ 0x10, sz2 = lz ^ 0x20, sz3 = lz ^ 0x30;
  const int sz4 = lz ^ 0x40, sz5 = lz ^ 0x50, sz6 = lz ^ 0x60, sz7 = lz ^ 0x70;

  const char* xbase = (const char*)(x + (size_t)tokBase * DDIM + kh * 2048);
  const short* wch = ws + kh * 131072 + l * 8;   // advances 16384 shorts/macro

  f32x4 acc0 = {0,0,0,0}, acc1 = {0,0,0,0}, acc2 = {0,0,0,0}, acc3 = {0,0,0,0};
  bf16x8 wset[3][8];

#define STG(DSTOFF, KOFF)                                                      \
  { char* d_ = (char*)ldsbuf + (DSTOFF); const char* s_ = xbase + (KOFF);      \
    gld_lds16((const float*)(s_ +  0 * 16384 + sz0), d_ +  0 * 1024);          \
    gld_lds16((const float*)(s_ +  1 * 16384 + sz1), d_ +  1 * 1024);          \
    gld_lds16((const float*)(s_ +  2 * 16384 + sz2), d_ +  2 * 1024);          \
    gld_lds16((const float*)(s_ +  3 * 16384 + sz3), d_ +  3 * 1024);          \
    gld_lds16((const float*)(s_ +  4 * 16384 + sz4), d_ +  4 * 1024);          \
    gld_lds16((const float*)(s_ +  5 * 16384 + sz5), d_ +  5 * 1024);          \
    gld_lds16((const float*)(s_ +  6 * 16384 + sz6), d_ +  6 * 1024);          \
    gld_lds16((const float*)(s_ +  7 * 16384 + sz7), d_ +  7 * 1024);          \
    gld_lds16((const float*)(s_ +  8 * 16384 + sz0), d_ +  8 * 1024);          \
    gld_lds16((const float*)(s_ +  9 * 16384 + sz1), d_ +  9 * 1024);          \
    gld_lds16((const float*)(s_ + 10 * 16384 + sz2), d_ + 10 * 1024);          \
    gld_lds16((const float*)(s_ + 11 * 16384 + sz3), d_ + 11 * 1024);          \
    gld_lds16((const float*)(s_ + 12 * 16384 + sz4), d_ + 12 * 1024);          \
    gld_lds16((const float*)(s_ + 13 * 16384 + sz5), d_ + 13 * 1024);          \
    gld_lds16((const float*)(s_ + 14 * 16384 + sz6), d_ + 14 * 1024);          \
    gld_lds16((const float*)(s_ + 15 * 16384 + sz7), d_ + 15 * 1024); }

#define LDW(SET, J)                                                            \
  { asm volatile("" ::: "memory");                                             \
    wset[SET][0] = *(const bf16x8*)(wch + (J) * 2048 + 0 * 512);               \
    wset[SET][1] = *(const bf16x8*)(wch + WS_LO + (J) * 2048 + 0 * 512);       \
    wset[SET][2] = *(const bf16x8*)(wch + (J) * 2048 + 1 * 512);               \
    wset[SET][3] = *(const bf16x8*)(wch + WS_LO + (J) * 2048 + 1 * 512);       \
    wset[SET][4] = *(const bf16x8*)(wch + (J) * 2048 + 2 * 512);               \
    wset[SET][5] = *(const bf16x8*)(wch + WS_LO + (J) * 2048 + 2 * 512);       \
    wset[SET][6] = *(const bf16x8*)(wch + (J) * 2048 + 3 * 512);               \
    wset[SET][7] = *(const bf16x8*)(wch + WS_LO + (J) * 2048 + 3 * 512);       \
    asm volatile("" ::: "memory"); }

#define MM(G, SET)                                                             \
  acc##G = __builtin_amdgcn_mfma_f32_16x16x32_bf16(ahi, wset[SET][2*(G)],   acc##G, 0, 0, 0); \
  acc##G = __builtin_amdgcn_mfma_f32_16x16x32_bf16(ahi, wset[SET][2*(G)+1], acc##G, 0, 0, 0); \
  acc##G = __builtin_amdgcn_mfma_f32_16x16x32_bf16(alo, wset[SET][2*(G)],   acc##G, 0, 0, 0);

#define SUB(S, SET, WAITN)                                                     \
  { asm volatile("s_waitcnt vmcnt(" #WAITN ")" ::: "memory");                  \
    unsigned a0_ = abase + curOff + (S) * 128 + lofs;                          \
    unsigned a1_ = a0_ ^ 16;                                                   \
    f32x4 f0, f1;                                                              \
    asm volatile("ds_read_b128 %0, %2\n\tds_read_b128 %1, %3"                  \
                 : "=&v"(f0), "=&v"(f1) : "v"(a0_), "v"(a1_));                 \
    asm volatile("s_waitcnt lgkmcnt(0)" ::: "memory");                         \
    __builtin_amdgcn_sched_barrier(0);                                         \
    uint2 h0_, s0_, h1_, s1_;                                                  \
    split4v(f0, h0_, s0_); split4v(f1, h1_, s1_);                              \
    bf16x8 ahi = mk8(h0_, h1_), alo = mk8(s0_, s1_);                           \
    MM(0, SET) MM(1, SET) MM(2, SET) MM(3, SET) }

  // prologue: X(0)
  STG(kh * 32768, 0)
  unsigned curOff = 0;

  for (int M = 0; M < 8; ++M) {
    asm volatile("s_waitcnt vmcnt(0)" ::: "memory");   // X(M) landed in LDS
    LDW(0, 0) LDW(1, 1)
    LDW(2, 2) SUB(0, 0, 16)
    LDW(0, 3) SUB(1, 1, 16)
    LDW(1, 4) SUB(2, 2, 16)
    LDW(2, 5) SUB(3, 0, 16)
    LDW(0, 6) SUB(4, 1, 16)
    LDW(1, 7)
    {
      const int nk = (M < 7) ? (M + 1) * 1024 : 7 * 1024;  // tail: L2-hot re-read into dead slot
      asm volatile("" ::: "memory");
      STG(kh * 32768 + (curOff ^ 16384u), nk)
      asm volatile("" ::: "memory");
    }
    SUB(5, 2, 32)
    SUB(6, 0, 24)
    SUB(7, 1, 16)
    wch += 16384;        // next 8 chunks of W
    curOff ^= 16384u;
  }

  // ---- combine K-halves; epilogue (rings dead after barrier drain) ----
  __syncthreads();
  float* part = (float*)ldsbuf;                 // [g*4+r][64] = 4 KB
  if (kh == 1) {
#pragma unroll
    for (int r = 0; r < 4; ++r) {
      part[(0 * 4 + r) * 64 + l] = acc0[r];
      part[(1 * 4 + r) * 64 + l] = acc1[r];
      part[(2 * 4 + r) * 64 + l] = acc2[r];
      part[(3 * 4 + r) * 64 + l] = acc3[r];
    }
  }
  __syncthreads();
  float* Lg = (float*)(ldsbuf + 16384);         // [16][68]
  if (kh == 0) {
    const int e = l & 15;
#pragma unroll
    for (int r = 0; r < 4; ++r) {
      const int t = hq * 4 + r;
      Lg[t * 68 +  0 + e] = acc0[r] + part[(0 * 4 + r) * 64 + l];
      Lg[t * 68 + 16 + e] = acc1[r] + part[(1 * 4 + r) * 64 + l];
      Lg[t * 68 + 32 + e] = acc2[r] + part[(2 * 4 + r) * 64 + l];
      Lg[t * 68 + 48 + e] = acc3[r] + part[(3 * 4 + r) * 64 + l];
    }
  }
  __syncthreads();

  float* out_idx = out;
  float* out_wt  = out + NTOK * 2;
  float* out_lg  = out + NTOK * 4;

  // 8 threads per token: top-4 of 64 + near-tie flag + fixup
  {
    const int t = u >> 3;        // token 0..15
    const int p = u & 7;
    float4 q0 = *(const float4*)&Lg[t * 68 + p * 8];
    float4 q1 = *(const float4*)&Lg[t * 68 + p * 8 + 4];

    float* dst = out_lg + (size_t)(tokBase + t) * NEXP + p * 8;
    *(float4*)dst = q0;
    *(float4*)(dst + 4) = q1;

    int base = p * 8;
    float a0 = q0.x, a1 = q0.y, a2 = q0.z, a3 = q0.w;
    int   ia0 = base, ia1 = base + 1, ia2 = base + 2, ia3 = base + 3;
    float b0 = q1.x, b1 = q1.y, b2 = q1.z, b3 = q1.w;
    int   ib0 = base + 4, ib1 = base + 5, ib2 = base + 6, ib3 = base + 7;
    CE(a0, ia0, a1, ia1) CE(a2, ia2, a3, ia3) CE(a0, ia0, a2, ia2) CE(a1, ia1, a3, ia3) CE(a1, ia1, a2, ia2)
    CE(b0, ib0, b1, ib1) CE(b2, ib2, b3, ib3) CE(b0, ib0, b2, ib2) CE(b1, ib1, b3, ib3) CE(b1, ib1, b2, ib2)
    CE(a0, ia0, b3, ib3) CE(a1, ia1, b2, ib2) CE(a2, ia2, b1, ib1) CE(a3, ia3, b0, ib0)
    CE(a0, ia0, a2, ia2) CE(a1, ia1, a3, ia3) CE(a0, ia0, a1, ia1) CE(a2, ia2, a3, ia3)

#pragma unroll
    for (int m = 1; m <= 4; m <<= 1) {
      float p0 = __shfl_xor(a0, m), p1 = __shfl_xor(a1, m);
      float p2 = __shfl_xor(a2, m), p3 = __shfl_xor(a3, m);
      int j0 = __shfl_xor(ia0, m), j1 = __shfl_xor(ia1, m);
      int j2 = __shfl_xor(ia2, m), j3 = __shfl_xor(ia3, m);
      CE(a0, ia0, p3, j3) CE(a1, ia1, p2, j2) CE(a2, ia2, p1, j1) CE(a3, ia3, p0, j0)
      CE(a0, ia0, a2, ia2) CE(a1, ia1, a3, ia3) CE(a0, ia0, a1, ia1) CE(a2, ia2, a3, ia3)
    }

    bool flag = false;
    unsigned pk = 0;
    if (p == 0) {
      flag = (a0 - a1 < TAU) || (a1 - a2 < TAU) || (a2 - a3 < TAU);
      pk = (unsigned)ia0 | ((unsigned)ia1 << 8) | ((unsigned)ia2 << 16) | ((unsigned)ia3 << 24);
      if (!flag) {
        const int tok = tokBase + t;
        float ex = expf(a1 - a0);
        float den = 1.0f + ex;
        out_idx[tok * 2 + 0] = (float)ia0;
        out_idx[tok * 2 + 1] = (float)ia1;
        out_wt[tok * 2 + 0]  = 1.0f / den;
        out_wt[tok * 2 + 1]  = ex / den;
      }
    }
    unsigned long long mk = __ballot(flag);
    while (mk) {
      const int src = __builtin_ctzll(mk);
      mk &= mk - 1;
      const unsigned pks = (unsigned)__shfl((int)pk, src);
      fixup_token(x, wgt, out_idx, out_wt, tokBase + kh * 8 + (src >> 3), pks, l);
    }
  }
}

extern "C" void kernel_launch(void* const* d_in, const int* in_sizes, int n_in,
                              void* d_out, int out_size, void* d_ws, size_t ws_size,
                              hipStream_t stream) {
  const float* x = (const float*)d_in[0];   // [4,4096,4096] f32
  const float* w = (const float*)d_in[1];   // [64,4096] f32
  float* out = (float*)d_out;               // 32768 idx + 32768 wt + 1048576 logits (all f32)
  short* ws = (short*)d_ws;                 // 1 MiB: bf16 hi/lo planes of W

  hipLaunchKernelGGL(presplit_w, dim3(128), dim3(256), 0, stream, w, ws);
  hipLaunchKernelGGL(router_main, dim3(NTOK / 16), dim3(128), 0, stream, x, w, ws, out);
}

// Round 9
// 103.069 us; speedup vs baseline: 1.1274x; 1.1274x over previous
//
#include <hip/hip_runtime.h>
#include <math.h>

#define NTOK 16384
#define DDIM 4096
#define NEXP 64
#define TAU  2e-4f
#define WS_LO 262144   // short-offset of the lo-plane inside d_ws
#define NCW  32        // chunks per K-quarter (1024 k / 32)

typedef short bf16x8 __attribute__((ext_vector_type(8)));
typedef float f32x4  __attribute__((ext_vector_type(4)));

__device__ __forceinline__ unsigned short bf16_rne(float f) {
  unsigned u = __float_as_uint(f);
  u += 0x7fffu + ((u >> 16) & 1u);
  return (unsigned short)(u >> 16);
}

__device__ __forceinline__ void split4(float4 v, uint2& hi, uint2& lo) {
  unsigned h0 = bf16_rne(v.x), h1 = bf16_rne(v.y), h2 = bf16_rne(v.z), h3 = bf16_rne(v.w);
  float r0 = v.x - __uint_as_float(h0 << 16);
  float r1 = v.y - __uint_as_float(h1 << 16);
  float r2 = v.z - __uint_as_float(h2 << 16);
  float r3 = v.w - __uint_as_float(h3 << 16);
  unsigned l0 = bf16_rne(r0), l1 = bf16_rne(r1), l2 = bf16_rne(r2), l3 = bf16_rne(r3);
  hi = make_uint2(h0 | (h1 << 16), h2 | (h3 << 16));
  lo = make_uint2(l0 | (l1 << 16), l2 | (l3 << 16));
}

__device__ __forceinline__ void split4v(f32x4 v, uint2& hi, uint2& lo) {
  unsigned h0 = bf16_rne(v[0]), h1 = bf16_rne(v[1]), h2 = bf16_rne(v[2]), h3 = bf16_rne(v[3]);
  float r0 = v[0] - __uint_as_float(h0 << 16);
  float r1 = v[1] - __uint_as_float(h1 << 16);
  float r2 = v[2] - __uint_as_float(h2 << 16);
  float r3 = v[3] - __uint_as_float(h3 << 16);
  unsigned l0 = bf16_rne(r0), l1 = bf16_rne(r1), l2 = bf16_rne(r2), l3 = bf16_rne(r3);
  hi = make_uint2(h0 | (h1 << 16), h2 | (h3 << 16));
  lo = make_uint2(l0 | (l1 << 16), l2 | (l3 << 16));
}

__device__ __forceinline__ bf16x8 mk8(uint2 a, uint2 b) {
  union { uint4 u; bf16x8 v; } t;
  t.u = make_uint4(a.x, a.y, b.x, b.y);
  return t.v;
}

__device__ __forceinline__ void gld_lds16(const float* g, char* l) {
  __builtin_amdgcn_global_load_lds((const __attribute__((address_space(1))) void*)g,
                                   (__attribute__((address_space(3))) void*)l,
                                   16, 0, 0);
}

__device__ __forceinline__ bool better(float va, int ia, float vb, int ib) {
  return (va > vb) || (va == vb && ia < ib);
}
__device__ __forceinline__ bool betterd(double va, int ia, double vb, int ib) {
  return (va > vb) || (va == vb && ia < ib);
}
#define CE(va, ia, vb, ib) { if (better(vb, ib, va, ia)) { float _tv = va; va = vb; vb = _tv; int _ti = ia; ia = ib; ib = _ti; } }

// ---- kernel 1: split W (fp32) into bf16 hi/lo, MFMA-fragment-linear, once ----
__global__ __launch_bounds__(256)
void presplit_w(const float* __restrict__ w, short* __restrict__ ws) {
  const int tid = blockIdx.x * 256 + threadIdx.x;  // 32768 threads
  const int e = tid >> 9;          // expert 0..63
  const int o = tid & 511;         // k-octet 0..511
  const int c = o >> 2, q = o & 3;
  const int l = (e & 15) + 16 * q;
  const int g = e >> 4;
  const float* src = w + (size_t)e * DDIM + o * 8;
  float4 v0 = *(const float4*)src;
  float4 v1 = *(const float4*)(src + 4);
  uint2 h0, s0, h1, s1;
  split4(v0, h0, s0);
  split4(v1, h1, s1);
  const int off = c * 2048 + g * 512 + l * 8;
  *(uint4*)(ws + off)         = make_uint4(h0.x, h0.y, h1.x, h1.y);
  *(uint4*)(ws + WS_LO + off) = make_uint4(s0.x, s0.y, s1.x, s1.y);
}

// ---- fp64 recompute for near-tie tokens (rare); executed by one full wave ----
__device__ __noinline__ void fixup_token(const float* __restrict__ x,
                                         const float* __restrict__ wgt,
                                         float* __restrict__ out_idx,
                                         float* __restrict__ out_wt,
                                         int tok, unsigned pk, int l) {
  const int e0 = pk & 255, e1 = (pk >> 8) & 255, e2 = (pk >> 16) & 255, e3 = (pk >> 24) & 255;
  const float* xr = x   + (size_t)tok * DDIM + l * 64;
  const float* w0 = wgt + (size_t)e0 * DDIM + l * 64;
  const float* w1 = wgt + (size_t)e1 * DDIM + l * 64;
  const float* w2 = wgt + (size_t)e2 * DDIM + l * 64;
  const float* w3 = wgt + (size_t)e3 * DDIM + l * 64;
  double s0 = 0.0, s1 = 0.0, s2 = 0.0, s3 = 0.0;
#pragma unroll 4
  for (int j = 0; j < 64; j += 4) {
    float4 xv = *(const float4*)(xr + j);
    float4 av = *(const float4*)(w0 + j);
    s0 = fma((double)xv.x, (double)av.x, s0); s0 = fma((double)xv.y, (double)av.y, s0);
    s0 = fma((double)xv.z, (double)av.z, s0); s0 = fma((double)xv.w, (double)av.w, s0);
    av = *(const float4*)(w1 + j);
    s1 = fma((double)xv.x, (double)av.x, s1); s1 = fma((double)xv.y, (double)av.y, s1);
    s1 = fma((double)xv.z, (double)av.z, s1); s1 = fma((double)xv.w, (double)av.w, s1);
    av = *(const float4*)(w2 + j);
    s2 = fma((double)xv.x, (double)av.x, s2); s2 = fma((double)xv.y, (double)av.y, s2);
    s2 = fma((double)xv.z, (double)av.z, s2); s2 = fma((double)xv.w, (double)av.w, s2);
    av = *(const float4*)(w3 + j);
    s3 = fma((double)xv.x, (double)av.x, s3); s3 = fma((double)xv.y, (double)av.y, s3);
    s3 = fma((double)xv.z, (double)av.z, s3); s3 = fma((double)xv.w, (double)av.w, s3);
  }
#pragma unroll
  for (int m = 1; m < 64; m <<= 1) {
    s0 += __shfl_xor(s0, m);
    s1 += __shfl_xor(s1, m);
    s2 += __shfl_xor(s2, m);
    s3 += __shfl_xor(s3, m);
  }
  if (l == 0) {
    double v0 = s0, v1 = s1, v2 = s2, v3 = s3;
    int i0 = e0, i1 = e1, i2 = e2, i3 = e3;
    if (betterd(v1, i1, v0, i0)) { double tv = v0; v0 = v1; v1 = tv; int ti = i0; i0 = i1; i1 = ti; }
    if (betterd(v3, i3, v2, i2)) { double tv = v2; v2 = v3; v3 = tv; int ti = i2; i2 = i3; i3 = ti; }
    if (betterd(v2, i2, v0, i0)) { double tv = v0; v0 = v2; v2 = tv; int ti = i0; i0 = i2; i2 = ti; }
    if (betterd(v3, i3, v1, i1)) { double tv = v1; v1 = v3; v3 = tv; int ti = i1; i1 = i3; i3 = ti; }
    if (betterd(v2, i2, v1, i1)) { double tv = v1; v1 = v2; v2 = tv; int ti = i1; i1 = i2; i2 = ti; }
    double ex = exp(v1 - v0);
    double den = 1.0 + ex;
    out_idx[tok * 2 + 0] = (float)i0;
    out_idx[tok * 2 + 1] = (float)i1;
    out_wt[tok * 2 + 0]  = (float)(1.0 / den);
    out_wt[tok * 2 + 1]  = (float)(ex / den);
  }
}

// ---- kernel 2: R7 pipeline, slimmed for occupancy ----
// 1024 blocks x 256 thr (4 waves = 4 K-quarters). Block = 16 tokens x 64 experts.
// Per wave: 4-slot x 2KB X ring (gld_lds, reader-lane-linear layout => conflict-free
// ds_read_b128 at l*16), W double-buffered in regs (2 sets = 64 VGPR). Barrier-free,
// uniform s_waitcnt vmcnt(14): per chunk 2 X + 8 W issues, X 3-ahead, W 2-ahead.
__global__ __launch_bounds__(256, 3)
void router_main(const float* __restrict__ x, const float* __restrict__ wgt,
                 const short* __restrict__ ws, float* __restrict__ out) {
  __shared__ __align__(16) char ldsbuf[32768];

  const int u = threadIdx.x;
  const int l = u & 63;
  const int wid = u >> 6;          // K-quarter 0..3
  const int tokBase = blockIdx.x * 16;

  char* ring = ldsbuf + wid * 8192;   // 4 slots x 2048 B
  const unsigned ldsbase =
      (unsigned)(size_t)(__attribute__((address_space(3))) char*)&ldsbuf[0];
  const unsigned rbase = ldsbase + wid * 8192 + l * 16;

  // k-phase rotation: block-local chunk t reads physical chunk (t+P)&31
  const int P = (blockIdx.x * 13) & 31;
#define PHYS(T) (((T) + P) & 31)

  // A-fragment sources: reader lane l wants X[tokBase+(l&15)][q*1024 + c*32 + (l>>4)*8 ..]
  const float* xbA = x + (size_t)(tokBase + (l & 15)) * DDIM + wid * 1024 + (l >> 4) * 8;
  const float* xbB = xbA + 4;

  const short* wch = ws + wid * 65536 + l * 8;

  f32x4 acc0 = {0,0,0,0}, acc1 = {0,0,0,0}, acc2 = {0,0,0,0}, acc3 = {0,0,0,0};
  bf16x8 wset[2][8];

#define LDW(SET, CC)                                                           \
  { asm volatile("" ::: "memory");                                             \
    wset[SET][0] = *(const bf16x8*)(wch + (CC) * 2048 + 0 * 512);              \
    wset[SET][1] = *(const bf16x8*)(wch + WS_LO + (CC) * 2048 + 0 * 512);      \
    wset[SET][2] = *(const bf16x8*)(wch + (CC) * 2048 + 1 * 512);              \
    wset[SET][3] = *(const bf16x8*)(wch + WS_LO + (CC) * 2048 + 1 * 512);      \
    wset[SET][4] = *(const bf16x8*)(wch + (CC) * 2048 + 2 * 512);              \
    wset[SET][5] = *(const bf16x8*)(wch + WS_LO + (CC) * 2048 + 2 * 512);      \
    wset[SET][6] = *(const bf16x8*)(wch + (CC) * 2048 + 3 * 512);              \
    wset[SET][7] = *(const bf16x8*)(wch + WS_LO + (CC) * 2048 + 3 * 512);      \
    asm volatile("" ::: "memory"); }

#define XISSUE(T, SLOT)                                                        \
  { const int cx_ = ((T) < NCW) ? (T) : NCW - 1;                               \
    const int cp_ = PHYS(cx_) * 32;                                            \
    char* d_ = ring + (SLOT) * 2048;                                           \
    gld_lds16(xbA + cp_, d_);                                                  \
    gld_lds16(xbB + cp_, d_ + 1024); }

#define MM(G, SET)                                                             \
  acc##G = __builtin_amdgcn_mfma_f32_16x16x32_bf16(ahi, wset[SET][2*(G)],   acc##G, 0, 0, 0); \
  acc##G = __builtin_amdgcn_mfma_f32_16x16x32_bf16(ahi, wset[SET][2*(G)+1], acc##G, 0, 0, 0); \
  acc##G = __builtin_amdgcn_mfma_f32_16x16x32_bf16(alo, wset[SET][2*(G)],   acc##G, 0, 0, 0);

// per step T: [2 gld X(T+3)] [vmcnt(14): X(T),W(T) done; X(T+1..T+3),W(T+1) airborne]
//             [asm ds_read x2 + lgkmcnt + sched_barrier] [split + 12 MFMA] [8 ld W(T+2)]
#define STEP(T, SLOT, SET)                                                     \
  {                                                                            \
    asm volatile("" ::: "memory");                                             \
    XISSUE((T) + 3, ((T) + 3) & 3)                                             \
    asm volatile("s_waitcnt vmcnt(14)" ::: "memory");                          \
    {                                                                          \
      f32x4 f0, f1;                                                            \
      unsigned a_ = rbase + (SLOT) * 2048;                                     \
      asm volatile("ds_read_b128 %0, %2\n\tds_read_b128 %1, %2 offset:1024"    \
                   : "=&v"(f0), "=&v"(f1) : "v"(a_));                          \
      asm volatile("s_waitcnt lgkmcnt(0)" ::: "memory");                       \
      __builtin_amdgcn_sched_barrier(0);                                       \
      uint2 h0_, s0_, h1_, s1_;                                                \
      split4v(f0, h0_, s0_); split4v(f1, h1_, s1_);                            \
      bf16x8 ahi = mk8(h0_, h1_), alo = mk8(s0_, s1_);                         \
      MM(0, SET) MM(1, SET) MM(2, SET) MM(3, SET)                              \
    }                                                                          \
    { const int cw_ = ((T) + 2 < NCW) ? (T) + 2 : NCW - 1;                     \
      LDW(SET, PHYS(cw_)) }                                                    \
  }

  // prologue FIFO: X0(2), W0(8), X1(2), W1(8), X2(2)  => 22 outstanding
  XISSUE(0, 0)
  LDW(0, PHYS(0))
  XISSUE(1, 1)
  LDW(1, PHYS(1))
  XISSUE(2, 2)

  for (int t = 0; t < NCW; t += 4) {
    STEP(t + 0, 0, 0)
    STEP(t + 1, 1, 1)
    STEP(t + 2, 2, 0)
    STEP(t + 3, 3, 1)
  }

  // ---- combine K-quarters through LDS (aliased over the rings) ----
  __syncthreads();   // drains vmcnt(0); all rings dead
  float* p = (float*)ldsbuf;
#define PIDX(KQ, G, R) (((((KQ) * 4 + (G)) * 4 + (R)) << 6) + l)
  {
#pragma unroll
    for (int r = 0; r < 4; ++r) {
      p[PIDX(wid, 0, r)] = acc0[r];
      p[PIDX(wid, 1, r)] = acc1[r];
      p[PIDX(wid, 2, r)] = acc2[r];
      p[PIDX(wid, 3, r)] = acc3[r];
    }
  }
  __syncthreads();

  float* out_idx = out;
  float* out_wt  = out + NTOK * 2;
  float* out_lg  = out + NTOK * 4;

  // wave `wid` handles accumulator row r = wid -> tokens (l>>4)*4 + wid
  float v0 = p[PIDX(0, 0, wid)] + p[PIDX(1, 0, wid)] + p[PIDX(2, 0, wid)] + p[PIDX(3, 0, wid)];
  float v1 = p[PIDX(0, 1, wid)] + p[PIDX(1, 1, wid)] + p[PIDX(2, 1, wid)] + p[PIDX(3, 1, wid)];
  float v2 = p[PIDX(0, 2, wid)] + p[PIDX(1, 2, wid)] + p[PIDX(2, 2, wid)] + p[PIDX(3, 2, wid)];
  float v3 = p[PIDX(0, 3, wid)] + p[PIDX(1, 3, wid)] + p[PIDX(2, 3, wid)] + p[PIDX(3, 3, wid)];

  const int tok = tokBase + (l >> 4) * 4 + wid;
  {
    float* dst = out_lg + (size_t)tok * NEXP + (l & 15);
    dst[0]  = v0;
    dst[16] = v1;
    dst[32] = v2;
    dst[48] = v3;
  }

  const int cbase = (l & 15);
  int i0 = cbase, i1 = cbase + 16, i2 = cbase + 32, i3 = cbase + 48;
  CE(v0, i0, v1, i1) CE(v2, i2, v3, i3) CE(v0, i0, v2, i2) CE(v1, i1, v3, i3) CE(v1, i1, v2, i2)
#pragma unroll
  for (int m = 1; m <= 8; m <<= 1) {
    float p0 = __shfl_xor(v0, m), p1 = __shfl_xor(v1, m);
    float p2 = __shfl_xor(v2, m), p3 = __shfl_xor(v3, m);
    int j0 = __shfl_xor(i0, m), j1 = __shfl_xor(i1, m);
    int j2 = __shfl_xor(i2, m), j3 = __shfl_xor(i3, m);
    CE(v0, i0, p3, j3) CE(v1, i1, p2, j2) CE(v2, i2, p1, j1) CE(v3, i3, p0, j0)
    CE(v0, i0, v2, i2) CE(v1, i1, v3, i3) CE(v0, i0, v1, i1) CE(v2, i2, v3, i3)
  }

  bool flag = false;
  unsigned pk = 0;
  if (cbase == 0) {
    flag = (v0 - v1 < TAU) || (v1 - v2 < TAU) || (v2 - v3 < TAU);
    pk = (unsigned)i0 | ((unsigned)i1 << 8) | ((unsigned)i2 << 16) | ((unsigned)i3 << 24);
    if (!flag) {
      float ex = expf(v1 - v0);
      float den = 1.0f + ex;
      out_idx[tok * 2 + 0] = (float)i0;
      out_idx[tok * 2 + 1] = (float)i1;
      out_wt[tok * 2 + 0]  = 1.0f / den;
      out_wt[tok * 2 + 1]  = ex / den;
    }
  }
  unsigned long long mk = __ballot(flag);
  while (mk) {
    const int src = __builtin_ctzll(mk);
    mk &= mk - 1;
    const unsigned pks = (unsigned)__shfl((int)pk, src);
    fixup_token(x, wgt, out_idx, out_wt, tokBase + (src >> 4) * 4 + wid, pks, l);
  }
}

extern "C" void kernel_launch(void* const* d_in, const int* in_sizes, int n_in,
                              void* d_out, int out_size, void* d_ws, size_t ws_size,
                              hipStream_t stream) {
  const float* x = (const float*)d_in[0];   // [4,4096,4096] f32
  const float* w = (const float*)d_in[1];   // [64,4096] f32
  float* out = (float*)d_out;               // 32768 idx + 32768 wt + 1048576 logits (all f32)
  short* ws = (short*)d_ws;                 // 1 MiB: bf16 hi/lo planes of W

  hipLaunchKernelGGL(presplit_w, dim3(128), dim3(256), 0, stream, w, ws);
  hipLaunchKernelGGL(router_main, dim3(NTOK / 16), dim3(256), 0, stream, x, w, ws, out);
}

// Round 10
// 91.290 us; speedup vs baseline: 1.2729x; 1.1290x over previous
//
#include <hip/hip_runtime.h>
#include <math.h>

#define NTOK 16384
#define DDIM 4096
#define NEXP 64
#define TAU  2e-4f
#define WS_LO 262144   // short-offset of the lo-plane inside d_ws
#define NCW  32        // chunks per K-quarter (1024 k / 32)

typedef short bf16x8 __attribute__((ext_vector_type(8)));
typedef float f32x4  __attribute__((ext_vector_type(4)));

__device__ __forceinline__ unsigned short bf16_rne(float f) {
  unsigned u = __float_as_uint(f);
  u += 0x7fffu + ((u >> 16) & 1u);
  return (unsigned short)(u >> 16);
}

__device__ __forceinline__ void split4(float4 v, uint2& hi, uint2& lo) {
  unsigned h0 = bf16_rne(v.x), h1 = bf16_rne(v.y), h2 = bf16_rne(v.z), h3 = bf16_rne(v.w);
  float r0 = v.x - __uint_as_float(h0 << 16);
  float r1 = v.y - __uint_as_float(h1 << 16);
  float r2 = v.z - __uint_as_float(h2 << 16);
  float r3 = v.w - __uint_as_float(h3 << 16);
  unsigned l0 = bf16_rne(r0), l1 = bf16_rne(r1), l2 = bf16_rne(r2), l3 = bf16_rne(r3);
  hi = make_uint2(h0 | (h1 << 16), h2 | (h3 << 16));
  lo = make_uint2(l0 | (l1 << 16), l2 | (l3 << 16));
}

__device__ __forceinline__ void split4v(f32x4 v, uint2& hi, uint2& lo) {
  unsigned h0 = bf16_rne(v[0]), h1 = bf16_rne(v[1]), h2 = bf16_rne(v[2]), h3 = bf16_rne(v[3]);
  float r0 = v[0] - __uint_as_float(h0 << 16);
  float r1 = v[1] - __uint_as_float(h1 << 16);
  float r2 = v[2] - __uint_as_float(h2 << 16);
  float r3 = v[3] - __uint_as_float(h3 << 16);
  unsigned l0 = bf16_rne(r0), l1 = bf16_rne(r1), l2 = bf16_rne(r2), l3 = bf16_rne(r3);
  hi = make_uint2(h0 | (h1 << 16), h2 | (h3 << 16));
  lo = make_uint2(l0 | (l1 << 16), l2 | (l3 << 16));
}

__device__ __forceinline__ bf16x8 mk8(uint2 a, uint2 b) {
  union { uint4 u; bf16x8 v; } t;
  t.u = make_uint4(a.x, a.y, b.x, b.y);
  return t.v;
}

__device__ __forceinline__ void gld_lds16(const float* g, char* l) {
  __builtin_amdgcn_global_load_lds((const __attribute__((address_space(1))) void*)g,
                                   (__attribute__((address_space(3))) void*)l,
                                   16, 0, 0);
}

__device__ __forceinline__ bool better(float va, int ia, float vb, int ib) {
  return (va > vb) || (va == vb && ia < ib);
}
__device__ __forceinline__ bool betterd(double va, int ia, double vb, int ib) {
  return (va > vb) || (va == vb && ia < ib);
}
#define CE(va, ia, vb, ib) { if (better(vb, ib, va, ia)) { float _tv = va; va = vb; vb = _tv; int _ti = ia; ia = ib; ib = _ti; } }

// ---- kernel 1: split W (fp32) into bf16 hi/lo, MFMA-fragment-linear, once ----
__global__ __launch_bounds__(256)
void presplit_w(const float* __restrict__ w, short* __restrict__ ws) {
  const int tid = blockIdx.x * 256 + threadIdx.x;  // 32768 threads
  const int e = tid >> 9;          // expert 0..63
  const int o = tid & 511;         // k-octet 0..511
  const int c = o >> 2, q = o & 3;
  const int l = (e & 15) + 16 * q;
  const int g = e >> 4;
  const float* src = w + (size_t)e * DDIM + o * 8;
  float4 v0 = *(const float4*)src;
  float4 v1 = *(const float4*)(src + 4);
  uint2 h0, s0, h1, s1;
  split4(v0, h0, s0);
  split4(v1, h1, s1);
  const int off = c * 2048 + g * 512 + l * 8;
  *(uint4*)(ws + off)         = make_uint4(h0.x, h0.y, h1.x, h1.y);
  *(uint4*)(ws + WS_LO + off) = make_uint4(s0.x, s0.y, s1.x, s1.y);
}

// ---- fp64 recompute for near-tie tokens (rare); executed by one full wave ----
__device__ __noinline__ void fixup_token(const float* __restrict__ x,
                                         const float* __restrict__ wgt,
                                         float* __restrict__ out_idx,
                                         float* __restrict__ out_wt,
                                         int tok, unsigned pk, int l) {
  const int e0 = pk & 255, e1 = (pk >> 8) & 255, e2 = (pk >> 16) & 255, e3 = (pk >> 24) & 255;
  const float* xr = x   + (size_t)tok * DDIM + l * 64;
  const float* w0 = wgt + (size_t)e0 * DDIM + l * 64;
  const float* w1 = wgt + (size_t)e1 * DDIM + l * 64;
  const float* w2 = wgt + (size_t)e2 * DDIM + l * 64;
  const float* w3 = wgt + (size_t)e3 * DDIM + l * 64;
  double s0 = 0.0, s1 = 0.0, s2 = 0.0, s3 = 0.0;
#pragma unroll 4
  for (int j = 0; j < 64; j += 4) {
    float4 xv = *(const float4*)(xr + j);
    float4 av = *(const float4*)(w0 + j);
    s0 = fma((double)xv.x, (double)av.x, s0); s0 = fma((double)xv.y, (double)av.y, s0);
    s0 = fma((double)xv.z, (double)av.z, s0); s0 = fma((double)xv.w, (double)av.w, s0);
    av = *(const float4*)(w1 + j);
    s1 = fma((double)xv.x, (double)av.x, s1); s1 = fma((double)xv.y, (double)av.y, s1);
    s1 = fma((double)xv.z, (double)av.z, s1); s1 = fma((double)xv.w, (double)av.w, s1);
    av = *(const float4*)(w2 + j);
    s2 = fma((double)xv.x, (double)av.x, s2); s2 = fma((double)xv.y, (double)av.y, s2);
    s2 = fma((double)xv.z, (double)av.z, s2); s2 = fma((double)xv.w, (double)av.w, s2);
    av = *(const float4*)(w3 + j);
    s3 = fma((double)xv.x, (double)av.x, s3); s3 = fma((double)xv.y, (double)av.y, s3);
    s3 = fma((double)xv.z, (double)av.z, s3); s3 = fma((double)xv.w, (double)av.w, s3);
  }
#pragma unroll
  for (int m = 1; m < 64; m <<= 1) {
    s0 += __shfl_xor(s0, m);
    s1 += __shfl_xor(s1, m);
    s2 += __shfl_xor(s2, m);
    s3 += __shfl_xor(s3, m);
  }
  if (l == 0) {
    double v0 = s0, v1 = s1, v2 = s2, v3 = s3;
    int i0 = e0, i1 = e1, i2 = e2, i3 = e3;
    if (betterd(v1, i1, v0, i0)) { double tv = v0; v0 = v1; v1 = tv; int ti = i0; i0 = i1; i1 = ti; }
    if (betterd(v3, i3, v2, i2)) { double tv = v2; v2 = v3; v3 = tv; int ti = i2; i2 = i3; i3 = ti; }
    if (betterd(v2, i2, v0, i0)) { double tv = v0; v0 = v2; v2 = tv; int ti = i0; i0 = i2; i2 = ti; }
    if (betterd(v3, i3, v1, i1)) { double tv = v1; v1 = v3; v3 = tv; int ti = i1; i1 = i3; i3 = ti; }
    if (betterd(v2, i2, v1, i1)) { double tv = v1; v1 = v2; v2 = tv; int ti = i1; i1 = i2; i2 = ti; }
    double ex = exp(v1 - v0);
    double den = 1.0 + ex;
    out_idx[tok * 2 + 0] = (float)i0;
    out_idx[tok * 2 + 1] = (float)i1;
    out_wt[tok * 2 + 0]  = (float)(1.0 / den);
    out_wt[tok * 2 + 1]  = (float)(ex / den);
  }
}

// ---- kernel 2: 64-token waves — W:X vector-traffic 1:1 ----
// 256 blocks x 256 thr (4 waves = 4 K-quarters). Block = 64 tokens x 64 experts.
// Per wave per 32k-chunk: X 8 KB (4 token-tiles, gld_lds fragment-linear) +
// W 8 KB (8 b128, dbuf). Barrier-free; uniform s_waitcnt vmcnt(16).
// LDS: 4 waves x 2 slots x 8 KB = 64 KB -> 2 blocks/CU (8 waves/CU).
__global__ __launch_bounds__(256, 2)
void router_main(const float* __restrict__ x, const float* __restrict__ wgt,
                 const short* __restrict__ ws, float* __restrict__ out) {
  __shared__ __align__(16) char ldsbuf[65536];

  const int u = threadIdx.x;
  const int l = u & 63;
  const int wid = u >> 6;          // K-quarter 0..3
  const int tokBase = blockIdx.x * 64;

  char* ring = ldsbuf + wid * 16384;   // 2 slots x 8192 B
  const unsigned ldsbase =
      (unsigned)(size_t)(__attribute__((address_space(3))) char*)&ldsbuf[0];
  const unsigned rbase = ldsbase + wid * 16384 + l * 16;

  // k-phase rotation across blocks
  const int P = (blockIdx.x * 13) & 31;
#define PHYS(T) (((T) + P) & 31)

  // A-fragment sources per token-tile: lane l = row (l&15), k-oct (l>>4)*8
  const float* xA0 = x + (size_t)(tokBase +  0 + (l & 15)) * DDIM + wid * 1024 + (l >> 4) * 8;
  const float* xB0 = xA0 + 4;
  const float* xA1 = x + (size_t)(tokBase + 16 + (l & 15)) * DDIM + wid * 1024 + (l >> 4) * 8;
  const float* xB1 = xA1 + 4;
  const float* xA2 = x + (size_t)(tokBase + 32 + (l & 15)) * DDIM + wid * 1024 + (l >> 4) * 8;
  const float* xB2 = xA2 + 4;
  const float* xA3 = x + (size_t)(tokBase + 48 + (l & 15)) * DDIM + wid * 1024 + (l >> 4) * 8;
  const float* xB3 = xA3 + 4;

  const short* wch = ws + wid * 65536 + l * 8;

  f32x4 acc[4][4];   // [token-tile][expert-group], all indices compile-time
#pragma unroll
  for (int t2 = 0; t2 < 4; ++t2)
#pragma unroll
    for (int g = 0; g < 4; ++g) acc[t2][g] = (f32x4){0.f, 0.f, 0.f, 0.f};

  bf16x8 wset[2][8];

#define LDW(SET, T)                                                            \
  { const int cw_ = ((T) < NCW) ? (T) : NCW - 1;                               \
    const int cc_ = PHYS(cw_);                                                 \
    asm volatile("" ::: "memory");                                             \
    wset[SET][0] = *(const bf16x8*)(wch + cc_ * 2048 + 0 * 512);               \
    wset[SET][1] = *(const bf16x8*)(wch + WS_LO + cc_ * 2048 + 0 * 512);       \
    wset[SET][2] = *(const bf16x8*)(wch + cc_ * 2048 + 1 * 512);               \
    wset[SET][3] = *(const bf16x8*)(wch + WS_LO + cc_ * 2048 + 1 * 512);       \
    wset[SET][4] = *(const bf16x8*)(wch + cc_ * 2048 + 2 * 512);               \
    wset[SET][5] = *(const bf16x8*)(wch + WS_LO + cc_ * 2048 + 2 * 512);       \
    wset[SET][6] = *(const bf16x8*)(wch + cc_ * 2048 + 3 * 512);               \
    wset[SET][7] = *(const bf16x8*)(wch + WS_LO + cc_ * 2048 + 3 * 512);       \
    asm volatile("" ::: "memory"); }

#define XISSUE(T, SLOT)                                                        \
  { const int cx_ = ((T) < NCW) ? (T) : NCW - 1;                               \
    const int cp_ = PHYS(cx_) * 32;                                            \
    char* d_ = ring + (SLOT) * 8192;                                           \
    gld_lds16(xA0 + cp_, d_);                                                  \
    gld_lds16(xB0 + cp_, d_ + 1024);                                           \
    gld_lds16(xA1 + cp_, d_ + 2048);                                           \
    gld_lds16(xB1 + cp_, d_ + 3072);                                           \
    gld_lds16(xA2 + cp_, d_ + 4096);                                           \
    gld_lds16(xB2 + cp_, d_ + 5120);                                           \
    gld_lds16(xA3 + cp_, d_ + 6144);                                           \
    gld_lds16(xB3 + cp_, d_ + 7168); }

#define MM(T2, G, SET)                                                         \
  acc[T2][G] = __builtin_amdgcn_mfma_f32_16x16x32_bf16(ahi, wset[SET][2*(G)],   acc[T2][G], 0, 0, 0); \
  acc[T2][G] = __builtin_amdgcn_mfma_f32_16x16x32_bf16(ahi, wset[SET][2*(G)+1], acc[T2][G], 0, 0, 0); \
  acc[T2][G] = __builtin_amdgcn_mfma_f32_16x16x32_bf16(alo, wset[SET][2*(G)],   acc[T2][G], 0, 0, 0);

#define COMPT(T2, SET, F0, F1)                                                 \
  { uint2 h0_, s0_, h1_, s1_;                                                  \
    split4v(F0, h0_, s0_); split4v(F1, h1_, s1_);                              \
    bf16x8 ahi = mk8(h0_, h1_), alo = mk8(s0_, s1_);                           \
    MM(T2, 0, SET) MM(T2, 1, SET) MM(T2, 2, SET) MM(T2, 3, SET) }

// per step T: [vmcnt(16): X(T),W(T) landed; X(T+1),W(T+1) airborne]
//             [8 ds_read staggered] [issue X(T+2) into slot T&1 after reads done]
//             [compute 4 tiles] [LDW W(T+2) into set T&1]
#define STEP(T, SLOT, SET)                                                     \
  {                                                                            \
    asm volatile("s_waitcnt vmcnt(16)" ::: "memory");                          \
    f32x4 f0, f1, f2, f3, f4, f5, f6, f7;                                      \
    { unsigned a_ = rbase + (SLOT) * 8192;                                     \
      asm volatile("ds_read_b128 %0, %2\n\tds_read_b128 %1, %2 offset:1024"    \
                   : "=&v"(f0), "=&v"(f1) : "v"(a_));                          \
      asm volatile("ds_read_b128 %0, %2 offset:2048\n\tds_read_b128 %1, %2 offset:3072" \
                   : "=&v"(f2), "=&v"(f3) : "v"(a_));                          \
      asm volatile("ds_read_b128 %0, %2 offset:4096\n\tds_read_b128 %1, %2 offset:5120" \
                   : "=&v"(f4), "=&v"(f5) : "v"(a_));                          \
      asm volatile("ds_read_b128 %0, %2 offset:6144\n\tds_read_b128 %1, %2 offset:7168" \
                   : "=&v"(f6), "=&v"(f7) : "v"(a_)); }                        \
    asm volatile("s_waitcnt lgkmcnt(0)" ::: "memory");                         \
    __builtin_amdgcn_sched_barrier(0);                                         \
    XISSUE((T) + 2, SLOT)                                                      \
    asm volatile("" ::: "memory");                                             \
    COMPT(0, SET, f0, f1)                                                      \
    COMPT(1, SET, f2, f3)                                                      \
    COMPT(2, SET, f4, f5)                                                      \
    COMPT(3, SET, f6, f7)                                                      \
    LDW(SET, (T) + 2)                                                          \
  }

  // prologue FIFO: X0(8), W0(8), X1(8), W1(8) = 32 outstanding
  XISSUE(0, 0)
  LDW(0, 0)
  XISSUE(1, 1)
  LDW(1, 1)

  for (int t = 0; t < NCW; t += 2) {
    STEP(t, 0, 0)
    STEP(t + 1, 1, 1)
  }

  // ---- combine K-quarters through LDS (aliased over the rings, 64 KB exactly) ----
  __syncthreads();   // per-wave vmcnt(0) drain before barrier: all dead gld_lds landed
  float* p = (float*)ldsbuf;
#define PIDX(KQ, T2, G, R) ((((((KQ) * 4 + (T2)) * 4 + (G)) * 4 + (R)) << 6) + l)
#pragma unroll
  for (int t2 = 0; t2 < 4; ++t2)
#pragma unroll
    for (int g = 0; g < 4; ++g)
#pragma unroll
      for (int r = 0; r < 4; ++r)
        p[PIDX(wid, t2, g, r)] = acc[t2][g][r];
  __syncthreads();

  float* out_idx = out;
  float* out_wt  = out + NTOK * 2;
  float* out_lg  = out + NTOK * 4;

  // wave `wid` handles accumulator row r = wid for all 4 token-tiles
#pragma unroll
  for (int t2 = 0; t2 < 4; ++t2) {
    float v0 = p[PIDX(0, t2, 0, wid)] + p[PIDX(1, t2, 0, wid)] + p[PIDX(2, t2, 0, wid)] + p[PIDX(3, t2, 0, wid)];
    float v1 = p[PIDX(0, t2, 1, wid)] + p[PIDX(1, t2, 1, wid)] + p[PIDX(2, t2, 1, wid)] + p[PIDX(3, t2, 1, wid)];
    float v2 = p[PIDX(0, t2, 2, wid)] + p[PIDX(1, t2, 2, wid)] + p[PIDX(2, t2, 2, wid)] + p[PIDX(3, t2, 2, wid)];
    float v3 = p[PIDX(0, t2, 3, wid)] + p[PIDX(1, t2, 3, wid)] + p[PIDX(2, t2, 3, wid)] + p[PIDX(3, t2, 3, wid)];

    const int tok = tokBase + t2 * 16 + (l >> 4) * 4 + wid;
    {
      float* dst = out_lg + (size_t)tok * NEXP + (l & 15);
      dst[0]  = v0;
      dst[16] = v1;
      dst[32] = v2;
      dst[48] = v3;
    }

    const int cbase = (l & 15);
    int i0 = cbase, i1 = cbase + 16, i2 = cbase + 32, i3 = cbase + 48;
    CE(v0, i0, v1, i1) CE(v2, i2, v3, i3) CE(v0, i0, v2, i2) CE(v1, i1, v3, i3) CE(v1, i1, v2, i2)
#pragma unroll
    for (int m = 1; m <= 8; m <<= 1) {
      float p0 = __shfl_xor(v0, m), p1 = __shfl_xor(v1, m);
      float p2 = __shfl_xor(v2, m), p3 = __shfl_xor(v3, m);
      int j0 = __shfl_xor(i0, m), j1 = __shfl_xor(i1, m);
      int j2 = __shfl_xor(i2, m), j3 = __shfl_xor(i3, m);
      CE(v0, i0, p3, j3) CE(v1, i1, p2, j2) CE(v2, i2, p1, j1) CE(v3, i3, p0, j0)
      CE(v0, i0, v2, i2) CE(v1, i1, v3, i3) CE(v0, i0, v1, i1) CE(v2, i2, v3, i3)
    }

    bool flag = false;
    unsigned pk = 0;
    if (cbase == 0) {
      flag = (v0 - v1 < TAU) || (v1 - v2 < TAU) || (v2 - v3 < TAU);
      pk = (unsigned)i0 | ((unsigned)i1 << 8) | ((unsigned)i2 << 16) | ((unsigned)i3 << 24);
      if (!flag) {
        float ex = expf(v1 - v0);
        float den = 1.0f + ex;
        out_idx[tok * 2 + 0] = (float)i0;
        out_idx[tok * 2 + 1] = (float)i1;
        out_wt[tok * 2 + 0]  = 1.0f / den;
        out_wt[tok * 2 + 1]  = ex / den;
      }
    }
    unsigned long long mk = __ballot(flag);
    while (mk) {
      const int src = __builtin_ctzll(mk);
      mk &= mk - 1;
      const unsigned pks = (unsigned)__shfl((int)pk, src);
      fixup_token(x, wgt, out_idx, out_wt, tokBase + t2 * 16 + (src >> 4) * 4 + wid, pks, l);
    }
  }
}

extern "C" void kernel_launch(void* const* d_in, const int* in_sizes, int n_in,
                              void* d_out, int out_size, void* d_ws, size_t ws_size,
                              hipStream_t stream) {
  const float* x = (const float*)d_in[0];   // [4,4096,4096] f32
  const float* w = (const float*)d_in[1];   // [64,4096] f32
  float* out = (float*)d_out;               // 32768 idx + 32768 wt + 1048576 logits (all f32)
  short* ws = (short*)d_ws;                 // 1 MiB: bf16 hi/lo planes of W

  hipLaunchKernelGGL(presplit_w, dim3(128), dim3(256), 0, stream, w, ws);
  hipLaunchKernelGGL(router_main, dim3(NTOK / 64), dim3(256), 0, stream, x, w, ws, out);
}